// Round 5
// baseline (259.883 us; speedup 1.0000x reference)
//
#include <hip/hip_runtime.h>
#include <hip/hip_bf16.h>
#include <stdint.h>

typedef __attribute__((ext_vector_type(8))) short short8;
typedef __attribute__((ext_vector_type(4))) short short4v;
typedef __attribute__((ext_vector_type(4))) float floatx4;
typedef __attribute__((ext_vector_type(4))) unsigned int uint4v;
typedef unsigned long long u64;

typedef __attribute__((address_space(1))) const uint32_t ga_u32;
typedef __attribute__((address_space(3))) uint32_t ls_u32;

static constexpr int NROWS = 32768;
static constexpr int NCODE = 8192;
static constexpr int QELEMS = 8388608;

static __device__ __forceinline__ short bf16bits(float v) {
  __hip_bfloat16 h = __float2bfloat16(v);
  return *reinterpret_cast<short*>(&h);
}

// ---- fused prep: [0,1024) z-transpose, [1024,3072) codebook, [3072,3088) amin init ----
__global__ __launch_bounds__(256) void prep_all(
    const float* __restrict__ z, const float* __restrict__ cb,
    __hip_bfloat16* __restrict__ zh, __hip_bfloat16* __restrict__ chv,
    float* __restrict__ norms, u64* __restrict__ amin)
{
  const int bid = blockIdx.x;
  const int t = threadIdx.x;
  if (bid < 1024) {
    // z (b,d,h,w) -> zh [n][d] bf16, vectorized both sides
    __shared__ float tile[32][260];
    const int b = bid & 31, db = (bid >> 5) & 7, hwb = bid >> 8;
    const int d0 = db * 32, hw0 = hwb * 256;
    const float* src = z + (((size_t)b * 256 + d0) << 10) + hw0;
#pragma unroll
    for (int i = 0; i < 8; ++i) {
      int idx = i * 256 + t;
      int r = idx >> 6, c4 = (idx & 63) * 4;
      *(floatx4*)&tile[r][c4] = *(const floatx4*)&src[((size_t)r << 10) + c4];
    }
    __syncthreads();
    const int dq = t & 3;       // which 8-d chunk
    const int hb = t >> 2;      // hw within group
#pragma unroll
    for (int it = 0; it < 4; ++it) {
      int h = hb + it * 64;
      short8 o;
#pragma unroll
      for (int i = 0; i < 8; ++i) o[i] = bf16bits(tile[dq * 8 + i][h]);
      *(short8*)&zh[((size_t)(b * 1024 + hw0 + h)) * 256 + d0 + dq * 8] = o;
    }
  } else if (bid < 3072) {
    // codebook -> bf16 + fp32 norms (4 codes per block, one wave each)
    const int k = (bid - 1024) * 4 + (t >> 6);
    const int lane = t & 63;
    floatx4 v = *(const floatx4*)&cb[((size_t)k << 8) + lane * 4];
    short4v o;
#pragma unroll
    for (int i = 0; i < 4; ++i) o[i] = bf16bits(v[i]);
    *(short4v*)&chv[((size_t)k << 8) + lane * 4] = o;
    float s = v[0] * v[0] + v[1] * v[1] + v[2] * v[2] + v[3] * v[3];
#pragma unroll
    for (int off = 32; off; off >>= 1) s += __shfl_down(s, off);
    if (lane == 0) norms[k] = s;
  } else {
    const int base = (bid - 3072) * 2048;
#pragma unroll
    for (int i = 0; i < 8; ++i) amin[base + i * 256 + t] = ~0ull;
  }
}

// ---- main: 128x256 tile, 4 waves, A direct-from-global, B in 4-slot LDS ring ----
// 2 blocks/CU (64 KiB LDS, <=256 VGPR): per-SIMD waves from DIFFERENT blocks
// overlap asynchronously (no shared barrier domain).
__global__ __launch_bounds__(256, 2) void gemm_argmin(
    const __hip_bfloat16* __restrict__ zh, const __hip_bfloat16* __restrict__ chv,
    const float* __restrict__ norms, u64* __restrict__ amin)
{
  __shared__ alignas(16) unsigned short lds[4 * 8192];  // 4 slots x 16 KiB (B only)

  const int tid = threadIdx.x;
  const int lane = tid & 63;
  const int wid = tid >> 6;
  const int wm = wid >> 1;  // code half (64 codes)
  const int wn = wid & 1;   // zrow half (128 zrows)

  // XCD chunked swizzle: 8192 blocks, XCD k owns cy in [16k,16k+16)
  const int bid = blockIdx.x;
  const int swz = (bid & 7) * 1024 + (bid >> 3);
  const int cx = swz & 63;
  const int cy = swz >> 6;
  const int m0 = cx * 128;
  const int n0 = cy * 256;

  const int q = lane & 15;
  const int g = lane >> 4;
  const int rchunk = ((g ^ ((q >> 1) & 3)) << 3);  // swizzled chunk (ushort units)

  // staging: 4 x global_load_lds(16B) per thread per kt; koff L-independent
  const int stRow = tid >> 2;
  const int stKoff = (((tid & 3) ^ ((tid >> 3) & 3)) << 3);

  floatx4 acc[4][8];
#pragma unroll
  for (int i = 0; i < 4; ++i)
#pragma unroll
    for (int j = 0; j < 8; ++j)
      acc[i][j] = (floatx4){0.f, 0.f, 0.f, 0.f};

  const __hip_bfloat16* aBase = chv + ((size_t)(m0 + wm * 64 + q) << 8) + g * 8;
  short8 af[2][4];

  auto LOAD_A = [&](int kt, int p) {  // codes: global -> VGPR (16-line wave gather)
#pragma unroll
    for (int i = 0; i < 4; ++i)
      af[p][i] = *(const short8*)(aBase + i * 4096 + kt * 32);
  };
  auto STAGE_B = [&](int kt) {
    const int slot = kt & 3;
#pragma unroll
    for (int L = 0; L < 4; ++L) {
      const __hip_bfloat16* gp = zh + ((size_t)(n0 + L * 64 + stRow) << 8) + kt * 32 + stKoff;
      __builtin_amdgcn_global_load_lds((ga_u32*)gp,
          (ls_u32*)(lds + slot * 8192 + L * 2048 + tid * 8), 16, 0, 0);
    }
  };

  // prologue FIFO: A0(4), B0(4), B1(4); vmcnt(4) drains A0+B0, leaves B1
  LOAD_A(0, 0);
  STAGE_B(0);
  STAGE_B(1);
  asm volatile("s_waitcnt vmcnt(4)" ::: "memory");
  __builtin_amdgcn_s_barrier();
  asm volatile("" ::: "memory");

#pragma unroll
  for (int kt = 0; kt < 8; ++kt) {
    const int slot = kt & 3;
    short8 bf[8];
#pragma unroll
    for (int j = 0; j < 8; ++j) {
      int row = wn * 128 + j * 16 + q;
      bf[j] = *(const short8*)(lds + slot * 8192 + row * 32 + rchunk);
    }
    if (kt < 6) STAGE_B(kt + 2);
    if (kt < 7) LOAD_A(kt + 1, (kt + 1) & 1);
    // FIFO at this point: B(kt+1),A(kt),B(kt+2),A(kt+1) -> vmcnt(8) drains
    // A(kt) (needed by this kt's MFMA) and B(kt+1) (needed after barrier).
    if (kt < 6)       asm volatile("s_waitcnt vmcnt(8)" ::: "memory");
    else if (kt == 6) asm volatile("s_waitcnt vmcnt(4)" ::: "memory");
    else              asm volatile("s_waitcnt vmcnt(0)" ::: "memory");
    __builtin_amdgcn_s_setprio(1);
#pragma unroll
    for (int i = 0; i < 4; ++i)
#pragma unroll
      for (int j = 0; j < 8; ++j)
        acc[i][j] = __builtin_amdgcn_mfma_f32_16x16x32_bf16(af[kt & 1][i], bf[j], acc[i][j], 0, 0, 0);
    __builtin_amdgcn_s_setprio(0);
    if (kt < 7) {
      asm volatile("" ::: "memory");
      __builtin_amdgcn_s_barrier();
      asm volatile("" ::: "memory");
    }
  }

  // ---- epilogue: fused argmin; ties -> smallest code; atomicMin (order-independent) ----
  float nrm[4][4];
#pragma unroll
  for (int i = 0; i < 4; ++i)
#pragma unroll
    for (int r = 0; r < 4; ++r)
      nrm[i][r] = norms[m0 + wm * 64 + i * 16 + g * 4 + r];

  u64* best2 = (u64*)lds;  // [256 zrows][2 wm]; slot0 region, no longer in use
#pragma unroll
  for (int j = 0; j < 8; ++j) {
    float best = __builtin_inff();
    int bc = 0;
#pragma unroll
    for (int i = 0; i < 4; ++i)
#pragma unroll
      for (int r = 0; r < 4; ++r) {
        float sc = fmaf(acc[i][j][r], -2.0f, nrm[i][r]);
        int cd = m0 + wm * 64 + i * 16 + g * 4 + r;
        if (sc < best) { best = sc; bc = cd; }
      }
    uint32_t u = __float_as_uint(best);
    u ^= ((uint32_t)((int32_t)u >> 31) | 0x80000000u);  // monotone-sortable
    u64 p = ((u64)u << 32) | (uint32_t)bc;
#pragma unroll
    for (int off = 16; off < 64; off <<= 1) {
      u64 o = (u64)__shfl_xor((long long)p, off);
      p = o < p ? o : p;
    }
    if (lane < 16) best2[(size_t)(wn * 128 + j * 16 + lane) * 2 + wm] = p;
  }
  __syncthreads();
  {
    u64 a = best2[tid * 2], b = best2[tid * 2 + 1];
    u64 p = a < b ? a : b;
    atomicMin(&amin[n0 + tid], p);
  }
}

// ---- pack: amin u64 -> code u32 ----
__global__ __launch_bounds__(256) void pack_codes(const u64* __restrict__ amin,
                                                  uint32_t* __restrict__ codei)
{
  const int i = blockIdx.x * 1024 + threadIdx.x;
#pragma unroll
  for (int k = 0; k < 4; ++k) codei[i + k * 256] = (uint32_t)amin[i + k * 256];
}

// ---- gather + output + per-block loss partials (8 elems/thread) ----
__global__ __launch_bounds__(256) void gather_out(
    const float* __restrict__ z, const float* __restrict__ cb,
    const uint32_t* __restrict__ codei,
    float* __restrict__ out, float* __restrict__ partial)
{
  const int t = threadIdx.x;
  const size_t e0 = ((size_t)blockIdx.x * 256 + t) * 8;
  const int d = (int)((e0 >> 10) & 255);
  const int b = (int)(e0 >> 18);
  const int n0 = b * 1024 + (int)(e0 & 1023);
  uint4v k0 = *(const uint4v*)&codei[n0];
  uint4v k1 = *(const uint4v*)&codei[n0 + 4];
  floatx4 z0 = *(const floatx4*)&z[e0];
  floatx4 z1 = *(const floatx4*)&z[e0 + 4];
  floatx4 q0, q1;
#pragma unroll
  for (int m = 0; m < 4; ++m) {
    q0[m] = cb[((size_t)k0[m] << 8) + d];
    q1[m] = cb[((size_t)k1[m] << 8) + d];
  }
  *(floatx4*)&out[e0] = q0;
  *(floatx4*)&out[e0 + 4] = q1;
  float s = 0.f;
#pragma unroll
  for (int m = 0; m < 4; ++m) {
    float d0 = z0[m] - q0[m], d1 = z1[m] - q1[m];
    s += d0 * d0 + d1 * d1;
  }
#pragma unroll
  for (int off = 32; off; off >>= 1) s += __shfl_down(s, off);
  __shared__ float ps[4];
  if ((t & 63) == 0) ps[t >> 6] = s;
  __syncthreads();
  if (t == 0) partial[blockIdx.x] = ps[0] + ps[1] + ps[2] + ps[3];
}

// ---- deterministic final reduction + scalar outputs ----
__global__ __launch_bounds__(256) void finalize(const float* __restrict__ partial,
                                                float* __restrict__ out)
{
  const int t = threadIdx.x;
  float s = 0.f;
#pragma unroll
  for (int i = 0; i < 16; ++i) s += partial[i * 256 + t];
#pragma unroll
  for (int off = 32; off; off >>= 1) s += __shfl_down(s, off);
  __shared__ float ps[4];
  if ((t & 63) == 0) ps[t >> 6] = s;
  __syncthreads();
  if (t == 0) {
    float m = (ps[0] + ps[1] + ps[2] + ps[3]) / (float)QELEMS;
    out[QELEMS] = m;             // codebook_loss
    out[QELEMS + 1] = 0.2f * m;  // commitment_loss
  }
}

extern "C" void kernel_launch(void* const* d_in, const int* in_sizes, int n_in,
                              void* d_out, int out_size, void* d_ws, size_t ws_size,
                              hipStream_t stream)
{
  const float* z = (const float*)d_in[0];
  const float* cb = (const float*)d_in[1];
  float* out = (float*)d_out;
  char* ws = (char*)d_ws;

  // ws layout (bytes)
  __hip_bfloat16* zh = (__hip_bfloat16*)(ws + 0);          // 16,777,216
  __hip_bfloat16* chv = (__hip_bfloat16*)(ws + 16777216);  //  4,194,304
  float* norms = (float*)(ws + 20971520);                  //    131,072 (padded)
  u64* amin = (u64*)(ws + 21102592);                       //    262,144
  uint32_t* codei = (uint32_t*)(ws + 21364736);            //    131,072
  float* lpart = (float*)(ws + 21495808);                  //     16,384
  // total: 21,512,192 bytes

  prep_all<<<3088, 256, 0, stream>>>(z, cb, zh, chv, norms, amin);
  gemm_argmin<<<8192, 256, 0, stream>>>(zh, chv, norms, amin);
  pack_codes<<<32, 256, 0, stream>>>(amin, codei);
  gather_out<<<QELEMS / 2048, 256, 0, stream>>>(z, cb, codei, out, lpart);
  finalize<<<1, 256, 0, stream>>>(lpart, out);
}

// Round 6
// 216.186 us; speedup vs baseline: 1.2021x; 1.2021x over previous
//
#include <hip/hip_runtime.h>
#include <hip/hip_bf16.h>
#include <stdint.h>

typedef __attribute__((ext_vector_type(8))) short short8;
typedef __attribute__((ext_vector_type(4))) short short4v;
typedef __attribute__((ext_vector_type(4))) float floatx4;
typedef __attribute__((ext_vector_type(4))) unsigned int uint4v;
typedef unsigned long long u64;

typedef __attribute__((address_space(1))) const uint32_t ga_u32;
typedef __attribute__((address_space(3))) uint32_t ls_u32;

static constexpr int NROWS = 32768;
static constexpr int NCODE = 8192;
static constexpr int QELEMS = 8388608;

static __device__ __forceinline__ short bf16bits(float v) {
  __hip_bfloat16 h = __float2bfloat16(v);
  return *reinterpret_cast<short*>(&h);
}

// ---- fused prep: [0,1024) z-transpose, [1024,3072) codebook, [3072,3088) amin init ----
__global__ __launch_bounds__(256) void prep_all(
    const float* __restrict__ z, const float* __restrict__ cb,
    __hip_bfloat16* __restrict__ zh, __hip_bfloat16* __restrict__ chv,
    float* __restrict__ norms, u64* __restrict__ amin)
{
  const int bid = blockIdx.x;
  const int t = threadIdx.x;
  if (bid < 1024) {
    __shared__ float tile[32][260];
    const int b = bid & 31, db = (bid >> 5) & 7, hwb = bid >> 8;
    const int d0 = db * 32, hw0 = hwb * 256;
    const float* src = z + (((size_t)b * 256 + d0) << 10) + hw0;
#pragma unroll
    for (int i = 0; i < 8; ++i) {
      int idx = i * 256 + t;
      int r = idx >> 6, c4 = (idx & 63) * 4;
      *(floatx4*)&tile[r][c4] = *(const floatx4*)&src[((size_t)r << 10) + c4];
    }
    __syncthreads();
    const int dq = t & 3;
    const int hb = t >> 2;
#pragma unroll
    for (int it = 0; it < 4; ++it) {
      int h = hb + it * 64;
      short8 o;
#pragma unroll
      for (int i = 0; i < 8; ++i) o[i] = bf16bits(tile[dq * 8 + i][h]);
      *(short8*)&zh[((size_t)(b * 1024 + hw0 + h)) * 256 + d0 + dq * 8] = o;
    }
  } else if (bid < 3072) {
    const int k = (bid - 1024) * 4 + (t >> 6);
    const int lane = t & 63;
    floatx4 v = *(const floatx4*)&cb[((size_t)k << 8) + lane * 4];
    short4v o;
#pragma unroll
    for (int i = 0; i < 4; ++i) o[i] = bf16bits(v[i]);
    *(short4v*)&chv[((size_t)k << 8) + lane * 4] = o;
    float s = v[0] * v[0] + v[1] * v[1] + v[2] * v[2] + v[3] * v[3];
#pragma unroll
    for (int off = 32; off; off >>= 1) s += __shfl_down(s, off);
    if (lane == 0) norms[k] = s;
  } else {
    const int base = (bid - 3072) * 2048;
#pragma unroll
    for (int i = 0; i < 8; ++i) amin[base + i * 256 + t] = ~0ull;
  }
}

// ---- main: 128x256 tile, 4 waves, 3-slot LDS ring (72 KiB), 2 blocks/CU ----
// Two co-resident blocks per CU are independent barrier domains: one block's
// LDS-read/stage/wait phase overlaps the other's MFMA cluster (setprio-backed).
__global__ __launch_bounds__(256, 2) void gemm_argmin(
    const __hip_bfloat16* __restrict__ zh, const __hip_bfloat16* __restrict__ chv,
    const float* __restrict__ norms, u64* __restrict__ amin)
{
  // slot = 12288 ushorts (24 KiB): A[128][32] at +0, B[256][32] at +4096
  __shared__ alignas(16) unsigned short lds[3 * 12288];

  const int tid = threadIdx.x;
  const int lane = tid & 63;
  const int wid = tid >> 6;
  const int wm = wid >> 1;  // code half (64 codes)
  const int wn = wid & 1;   // zrow half (128 zrows)

  // XCD chunked swizzle: 8192 blocks; XCD k owns cy in [16k,16k+16)
  const int bid = blockIdx.x;
  const int swz = (bid & 7) * 1024 + (bid >> 3);
  const int cx = swz & 63;
  const int cy = swz >> 6;
  const int m0 = cx * 128;
  const int n0 = cy * 256;

  const int q = lane & 15;
  const int g = lane >> 4;
  const int rchunk = ((g ^ ((q >> 1) & 3)) << 3);  // swizzled chunk (ushort units)

  // staging: linear LDS dest, chunk-XOR pre-swizzled global source (rule #21 pair)
  const int stRow = tid >> 2;                               // 0..63
  const int stKoff = (((tid & 3) ^ ((tid >> 3) & 3)) << 3); // swizzled k-elem offset

  floatx4 acc[4][8];
#pragma unroll
  for (int i = 0; i < 4; ++i)
#pragma unroll
    for (int j = 0; j < 8; ++j)
      acc[i][j] = (floatx4){0.f, 0.f, 0.f, 0.f};

  auto STAGE = [&](int kt) {  // 6 x global_load_lds(16B): A 8KB + B 16KB
    const int slot = kt % 3;
    unsigned short* sA = lds + slot * 12288 + tid * 8;
    const __hip_bfloat16* gA = chv + ((size_t)(m0 + stRow) << 8) + kt * 32 + stKoff;
    __builtin_amdgcn_global_load_lds((ga_u32*)gA, (ls_u32*)sA, 16, 0, 0);
    __builtin_amdgcn_global_load_lds((ga_u32*)(gA + (64 << 8)), (ls_u32*)(sA + 2048), 16, 0, 0);
    unsigned short* sB = lds + slot * 12288 + 4096 + tid * 8;
    const __hip_bfloat16* gB = zh + ((size_t)(n0 + stRow) << 8) + kt * 32 + stKoff;
#pragma unroll
    for (int L = 0; L < 4; ++L)
      __builtin_amdgcn_global_load_lds((ga_u32*)(gB + (size_t)(L << 14)),
                                       (ls_u32*)(sB + L * 2048), 16, 0, 0);
  };

  // prologue: stage kt0, kt1; drain kt0 (6 of kt1 stay in flight)
  STAGE(0); STAGE(1);
  asm volatile("s_waitcnt vmcnt(6)" ::: "memory");
  __builtin_amdgcn_s_barrier();
  asm volatile("" ::: "memory");

#pragma unroll
  for (int kt = 0; kt < 8; ++kt) {
    const int slot = kt % 3;
    short8 af[4], bf[8];
#pragma unroll
    for (int i = 0; i < 4; ++i) {
      int row = wm * 64 + i * 16 + q;
      af[i] = *(const short8*)(lds + slot * 12288 + row * 32 + rchunk);
    }
#pragma unroll
    for (int j = 0; j < 8; ++j) {
      int row = wn * 128 + j * 16 + q;
      bf[j] = *(const short8*)(lds + slot * 12288 + 4096 + row * 32 + rchunk);
    }
    if (kt < 6) STAGE(kt + 2);
    __builtin_amdgcn_s_setprio(1);
#pragma unroll
    for (int i = 0; i < 4; ++i)
#pragma unroll
      for (int j = 0; j < 8; ++j)
        acc[i][j] = __builtin_amdgcn_mfma_f32_16x16x32_bf16(af[i], bf[j], acc[i][j], 0, 0, 0);
    __builtin_amdgcn_s_setprio(0);
    // boundary: drain kt+1 (6 loads), keep kt+2's 6 in flight
    if (kt < 6)       asm volatile("s_waitcnt vmcnt(6)" ::: "memory");
    else if (kt == 6) asm volatile("s_waitcnt vmcnt(0)" ::: "memory");
    asm volatile("" ::: "memory");
    __builtin_amdgcn_s_barrier();
    asm volatile("" ::: "memory");
  }

  // ---- epilogue: fused argmin; ties -> smallest code; atomicMin (order-independent) ----
  float nrm[4][4];
#pragma unroll
  for (int i = 0; i < 4; ++i)
#pragma unroll
    for (int r = 0; r < 4; ++r)
      nrm[i][r] = norms[m0 + wm * 64 + i * 16 + g * 4 + r];

  u64* best2 = (u64*)lds;  // [256 zrows][2 wm] (post-loop barrier protects reuse)
#pragma unroll
  for (int j = 0; j < 8; ++j) {
    float best = __builtin_inff();
    int bc = 0;
#pragma unroll
    for (int i = 0; i < 4; ++i)
#pragma unroll
      for (int r = 0; r < 4; ++r) {
        float sc = fmaf(acc[i][j][r], -2.0f, nrm[i][r]);
        int cd = m0 + wm * 64 + i * 16 + g * 4 + r;
        if (sc < best) { best = sc; bc = cd; }
      }
    uint32_t u = __float_as_uint(best);
    u ^= ((uint32_t)((int32_t)u >> 31) | 0x80000000u);  // monotone-sortable
    u64 p = ((u64)u << 32) | (uint32_t)bc;
#pragma unroll
    for (int off = 16; off < 64; off <<= 1) {
      u64 o = (u64)__shfl_xor((long long)p, off);
      p = o < p ? o : p;
    }
    if (lane < 16) best2[(size_t)(wn * 128 + j * 16 + lane) * 2 + wm] = p;
  }
  __syncthreads();
  {
    u64 a = best2[tid * 2], b = best2[tid * 2 + 1];
    u64 p = a < b ? a : b;
    atomicMin(&amin[n0 + tid], p);
  }
}

// ---- pack: amin u64 -> code u32 ----
__global__ __launch_bounds__(256) void pack_codes(const u64* __restrict__ amin,
                                                  uint32_t* __restrict__ codei)
{
  const int i = blockIdx.x * 1024 + threadIdx.x;
#pragma unroll
  for (int k = 0; k < 4; ++k) codei[i + k * 256] = (uint32_t)amin[i + k * 256];
}

// ---- gather + output + per-block loss partials (8 elems/thread) ----
__global__ __launch_bounds__(256) void gather_out(
    const float* __restrict__ z, const float* __restrict__ cb,
    const uint32_t* __restrict__ codei,
    float* __restrict__ out, float* __restrict__ partial)
{
  const int t = threadIdx.x;
  const size_t e0 = ((size_t)blockIdx.x * 256 + t) * 8;
  const int d = (int)((e0 >> 10) & 255);
  const int b = (int)(e0 >> 18);
  const int n0 = b * 1024 + (int)(e0 & 1023);
  uint4v k0 = *(const uint4v*)&codei[n0];
  uint4v k1 = *(const uint4v*)&codei[n0 + 4];
  floatx4 z0 = *(const floatx4*)&z[e0];
  floatx4 z1 = *(const floatx4*)&z[e0 + 4];
  floatx4 q0, q1;
#pragma unroll
  for (int m = 0; m < 4; ++m) {
    q0[m] = cb[((size_t)k0[m] << 8) + d];
    q1[m] = cb[((size_t)k1[m] << 8) + d];
  }
  *(floatx4*)&out[e0] = q0;
  *(floatx4*)&out[e0 + 4] = q1;
  float s = 0.f;
#pragma unroll
  for (int m = 0; m < 4; ++m) {
    float d0 = z0[m] - q0[m], d1 = z1[m] - q1[m];
    s += d0 * d0 + d1 * d1;
  }
#pragma unroll
  for (int off = 32; off; off >>= 1) s += __shfl_down(s, off);
  __shared__ float ps[4];
  if ((t & 63) == 0) ps[t >> 6] = s;
  __syncthreads();
  if (t == 0) partial[blockIdx.x] = ps[0] + ps[1] + ps[2] + ps[3];
}

// ---- deterministic final reduction + scalar outputs ----
__global__ __launch_bounds__(256) void finalize(const float* __restrict__ partial,
                                                float* __restrict__ out)
{
  const int t = threadIdx.x;
  float s = 0.f;
#pragma unroll
  for (int i = 0; i < 16; ++i) s += partial[i * 256 + t];
#pragma unroll
  for (int off = 32; off; off >>= 1) s += __shfl_down(s, off);
  __shared__ float ps[4];
  if ((t & 63) == 0) ps[t >> 6] = s;
  __syncthreads();
  if (t == 0) {
    float m = (ps[0] + ps[1] + ps[2] + ps[3]) / (float)QELEMS;
    out[QELEMS] = m;             // codebook_loss
    out[QELEMS + 1] = 0.2f * m;  // commitment_loss
  }
}

extern "C" void kernel_launch(void* const* d_in, const int* in_sizes, int n_in,
                              void* d_out, int out_size, void* d_ws, size_t ws_size,
                              hipStream_t stream)
{
  const float* z = (const float*)d_in[0];
  const float* cb = (const float*)d_in[1];
  float* out = (float*)d_out;
  char* ws = (char*)d_ws;

  // ws layout (bytes)
  __hip_bfloat16* zh = (__hip_bfloat16*)(ws + 0);          // 16,777,216
  __hip_bfloat16* chv = (__hip_bfloat16*)(ws + 16777216);  //  4,194,304
  float* norms = (float*)(ws + 20971520);                  //    131,072 (padded)
  u64* amin = (u64*)(ws + 21102592);                       //    262,144
  uint32_t* codei = (uint32_t*)(ws + 21364736);            //    131,072
  float* lpart = (float*)(ws + 21495808);                  //     16,384
  // total: 21,512,192 bytes

  prep_all<<<3088, 256, 0, stream>>>(z, cb, zh, chv, norms, amin);
  gemm_argmin<<<8192, 256, 0, stream>>>(zh, chv, norms, amin);
  pack_codes<<<32, 256, 0, stream>>>(amin, codei);
  gather_out<<<QELEMS / 2048, 256, 0, stream>>>(z, cb, codei, out, lpart);
  finalize<<<1, 256, 0, stream>>>(lpart, out);
}